// Round 1
// baseline (49.783 us; speedup 1.0000x reference)
//
#include <hip/hip_runtime.h>

#define SS 32
#define BB 128
#define VV 32000
#define EOS_ID 2
#define MAXK 128   // max stored candidates per row (mean ~20, 16-sigma safety)

// Kernel A: compact multi-hot targets[b,:] into per-b index lists.
// Grid: BB*8 blocks; block (b,chunk) scans 4000 elems as float4.
__global__ void ofl_compact(const float* __restrict__ tg,
                            int* __restrict__ cnt,
                            int* __restrict__ idxlist) {
    int b = blockIdx.x >> 3;
    int chunk = blockIdx.x & 7;
    const int elems = VV / 8;  // 4000, divisible by 4
    const float4* t4 = reinterpret_cast<const float4*>(tg + (size_t)b * VV + chunk * elems);
    for (int j = threadIdx.x; j < elems / 4; j += blockDim.x) {
        float4 v = t4[j];
        int e0 = chunk * elems + j * 4;
        if (v.x > 0.5f) { int s = atomicAdd(&cnt[b], 1); if (s < MAXK - 1) idxlist[b * MAXK + s] = e0;     }
        if (v.y > 0.5f) { int s = atomicAdd(&cnt[b], 1); if (s < MAXK - 1) idxlist[b * MAXK + s] = e0 + 1; }
        if (v.z > 0.5f) { int s = atomicAdd(&cnt[b], 1); if (s < MAXK - 1) idxlist[b * MAXK + s] = e0 + 2; }
        if (v.w > 0.5f) { int s = atomicAdd(&cnt[b], 1); if (s < MAXK - 1) idxlist[b * MAXK + s] = e0 + 3; }
    }
}

// Kernel B: one block per batch row. Gather all needed out-values into LDS,
// then wave 0 runs the 32-step greedy selection from LDS.
__global__ __launch_bounds__(256) void ofl_select(const float* __restrict__ out,
                                                  const int* __restrict__ cnt,
                                                  const int* __restrict__ idxlist,
                                                  float* __restrict__ sums) {
    __shared__ float G[SS][MAXK];   // 16 KiB: G[t][k] = out[t,b,idx[k]]; slot n = EOS
    __shared__ int sidx[MAXK];
    int b = blockIdx.x;
    int n = cnt[b];
    if (n > MAXK - 1) n = MAXK - 1;

    for (int k = threadIdx.x; k < n; k += blockDim.x) sidx[k] = idxlist[b * MAXK + k];
    __syncthreads();

    int tot = SS * (n + 1);
    for (int j = threadIdx.x; j < tot; j += blockDim.x) {
        int t = j / (n + 1);
        int k = j - t * (n + 1);
        int v = (k < n) ? sidx[k] : EOS_ID;
        G[t][k] = out[((size_t)t * BB + b) * VV + v];
    }
    __syncthreads();

    if (threadIdx.x < 64) {
        int lane = threadIdx.x;
        bool alive0 = lane < n;          // slot `lane`
        bool alive1 = (lane + 64) < n;   // slot `lane+64`
        int remaining = n;
        float acc = 0.f;
        for (int t = 0; t < SS; ++t) {
            float cv;
            if (remaining > 0) {
                float v0 = alive0 ? G[t][lane]      : -INFINITY;
                int   i0 = alive0 ? sidx[lane]      : 0x7fffffff;
                float v1 = alive1 ? G[t][lane + 64] : -INFINITY;
                int   i1 = alive1 ? sidx[lane + 64] : 0x7fffffff;
                float val; int vidx, pos;
                if (v1 > v0 || (v1 == v0 && i1 < i0)) { val = v1; vidx = i1; pos = lane + 64; }
                else                                   { val = v0; vidx = i0; pos = lane; }
                // 64-lane butterfly arg-max; tie-break: smaller vocab index
                for (int m = 1; m < 64; m <<= 1) {
                    float oval  = __shfl_xor(val,  m, 64);
                    int   ovidx = __shfl_xor(vidx, m, 64);
                    int   opos  = __shfl_xor(pos,  m, 64);
                    if (oval > val || (oval == val && ovidx < vidx)) {
                        val = oval; vidx = ovidx; pos = opos;
                    }
                }
                if (pos == lane)      alive0 = false;
                if (pos == lane + 64) alive1 = false;
                remaining--;
                cv = val;
            } else {
                cv = G[t][n];  // EOS picked forever once the set is exhausted
            }
            acc += cv;
        }
        if (lane == 0) sums[b] = acc;
    }
}

// Kernel C: deterministic serial reduction + final scaling.
__global__ void ofl_finalize(const float* __restrict__ sums, float* __restrict__ outp) {
    if (threadIdx.x == 0) {
        double s = 0.0;
        for (int b = 0; b < BB; ++b) s += (double)sums[b];
        outp[0] = (float)(-s / (double)(SS * BB));
    }
}

extern "C" void kernel_launch(void* const* d_in, const int* in_sizes, int n_in,
                              void* d_out, int out_size, void* d_ws, size_t ws_size,
                              hipStream_t stream) {
    const float* outputs = (const float*)d_in[0];   // [S,B,V] fp32 log-probs
    // d_in[1] = output_symbols (unused in executed branch)
    const float* targets = (const float*)d_in[2];   // [B,V] fp32 multi-hot

    int*   cnt     = (int*)d_ws;                    // 128 ints
    int*   idxlist = cnt + BB;                      // 128*128 ints
    float* sums    = (float*)(idxlist + BB * MAXK); // 128 floats

    hipMemsetAsync(cnt, 0, BB * sizeof(int), stream);
    ofl_compact<<<dim3(BB * 8), dim3(256), 0, stream>>>(targets, cnt, idxlist);
    ofl_select<<<dim3(BB), dim3(256), 0, stream>>>(outputs, cnt, idxlist, sums);
    ofl_finalize<<<dim3(1), dim3(64), 0, stream>>>(sums, (float*)d_out);
}